// Round 2
// baseline (852.091 us; speedup 1.0000x reference)
//
#include <hip/hip_runtime.h>

// AxialAttentionBlock mega-fused kernel.
// Key insight (round 0): the reference einsum labels make "attention" a
// PER-TOKEN 8x8 head-mix (softmax over k-heads at each position), and
// attn_h == attn_w, so out_attn = 2*attn @ w_out. Everything is token-local
// => one fused kernel per 64-token tile, all intermediates in LDS.
// Workspace use: only bf16-transposed weights (~1.5 MB).

#define T_TOK 131072  // B*H*W = 2*256*256

typedef __attribute__((ext_vector_type(8))) short bf16x8;
typedef __attribute__((ext_vector_type(4))) float f32x4;
typedef unsigned int u32;
typedef unsigned short u16;

__device__ __forceinline__ float bf2f(u32 u) {
  u32 v = u << 16;
  return __builtin_bit_cast(float, v);
}
__device__ __forceinline__ u16 f2bf(float f) {
  u32 u = __builtin_bit_cast(u32, f);
  return (u16)((u + 0x7fffu + ((u >> 16) & 1u)) >> 16);  // RNE
}
__device__ __forceinline__ float gelu_f(float x) {
  float t = 0.7978845608028654f * (x + 0.044715f * x * x * x);
  t = fminf(fmaxf(t, -15.f), 15.f);
  float e = __expf(2.0f * t);
  return 0.5f * x * (1.0f + (e - 1.0f) / (e + 1.0f));
}

// ---------------- weight prep: bf16 + transpose (ws: 1.5 MB) --------------
// wfT[n][k] (1792x256) = w_fused[k][n];  wcT[n][kk] (256x1280):
//   kk<256 -> w_out[kk][n], else w_mlp[kk-256][n]
__global__ __launch_bounds__(256) void kw_prep(
    const float* __restrict__ w_fused, const float* __restrict__ w_out,
    const float* __restrict__ w_mlp, u16* __restrict__ wfT,
    u16* __restrict__ wcT) {
  int idx = blockIdx.x * 256 + threadIdx.x;
  const int NFT = 1792 * 256;
  if (idx < NFT) {
    int n = idx >> 8, k = idx & 255;
    wfT[idx] = f2bf(w_fused[k * 1792 + n]);
  } else {
    int j = idx - NFT;
    if (j < 256 * 1280) {
      int n = j / 1280, kk = j % 1280;
      float v = (kk < 256) ? w_out[kk * 256 + n] : w_mlp[(kk - 256) * 256 + n];
      wcT[j] = f2bf(v);
    }
  }
}

// ---------------- LDS layout (u16 units), total 152,576 B -----------------
#define HS_OFF 0       // h tile:   64 x 264
#define Q_OFF 16896    // q tile:   64 x 264 (becomes attn2 in place)
#define K_OFF 33792    // k tile:   64 x 264
#define V_OFF 50688    // v tile:   64 x 264
#define WSM_OFF 67584  // GEMM1 B half-chunk: 64 x 136
#define LDS_U16 76288
// phase-3 overlays (k_s/v_s dead after attention):
#define GFF_OFF K_OFF            // gelu(ff) chunk: 64 x 72
#define WS2_OFF (K_OFF + 4608)   // GEMM2 B chunk: 256 x 72 (ends 56832)

// one GEMM1 chunk (64 N-cols x 256 K), staged in two K=128 halves
#define GEMM1_CHUNK(c_, A0, A1)                                              \
  do {                                                                       \
    _Pragma("unroll") for (int h = 0; h < 2; ++h) {                          \
      __syncthreads();                                                       \
      _Pragma("unroll") for (int it = 0; it < 2; ++it) {                     \
        int i = tid + it * 512;                                              \
        int r = i >> 4, jj = i & 15;                                         \
        *(uint4*)&L[WSM_OFF + r * 136 + jj * 8] =                            \
            *(const uint4*)(wfT + ((size_t)(c_)*64 + r) * 256 + h * 128 +    \
                            jj * 8);                                         \
      }                                                                      \
      __syncthreads();                                                       \
      _Pragma("unroll") for (int ks = 0; ks < 4; ++ks) {                     \
        bf16x8 a = *(const bf16x8*)&L[HS_OFF + (mrow + lr) * 264 +           \
                                      (h * 4 + ks) * 32 + lg * 8];           \
        bf16x8 b0 =                                                          \
            *(const bf16x8*)&L[WSM_OFF + (ncl + lr) * 136 + ks * 32 + lg * 8]; \
        bf16x8 b1 = *(const bf16x8*)&L[WSM_OFF + (ncl + 16 + lr) * 136 +     \
                                       ks * 32 + lg * 8];                    \
        A0 = __builtin_amdgcn_mfma_f32_16x16x32_bf16(a, b0, A0, 0, 0, 0);    \
        A1 = __builtin_amdgcn_mfma_f32_16x16x32_bf16(a, b1, A1, 0, 0, 0);    \
      }                                                                      \
    }                                                                        \
  } while (0)

__global__ __launch_bounds__(512, 2) void k_mega(
    const float* __restrict__ x, const float* __restrict__ g0,
    const u16* __restrict__ wfT, const u16* __restrict__ wcT,
    const float* __restrict__ b_fused, const float* __restrict__ lnq,
    const float* __restrict__ lnk, const float* __restrict__ b_out,
    const float* __restrict__ b_mlp, const float* __restrict__ gamma,
    float* __restrict__ out) {
  __shared__ u16 L[LDS_U16];
  const int tid = threadIdx.x;
  const size_t t0 = (size_t)blockIdx.x * 64;
  const int wv = tid >> 6, l = tid & 63, lr = l & 15, lg = l >> 4;
  const int mrow = (wv >> 1) * 16;
  const int ncl = (wv & 1) * 32;

  // ---- Phase 0: LN0 of the 64-token x tile -> hs (bf16) ----
  {
    int tok = tid >> 3, j = tid & 7;
    const float* xp = x + (t0 + tok) * 256 + j * 32;
    float v[32];
#pragma unroll
    for (int i = 0; i < 8; ++i) {
      float4 f = ((const float4*)xp)[i];
      v[4 * i] = f.x; v[4 * i + 1] = f.y; v[4 * i + 2] = f.z; v[4 * i + 3] = f.w;
    }
    float s = 0.f, ss = 0.f;
#pragma unroll
    for (int i = 0; i < 32; ++i) { s += v[i]; ss += v[i] * v[i]; }
#pragma unroll
    for (int m = 1; m < 8; m <<= 1) {
      s += __shfl_xor(s, m, 64);
      ss += __shfl_xor(ss, m, 64);
    }
    float mu = s * (1.0f / 256.0f);
    float rs = rsqrtf(ss * (1.0f / 256.0f) - mu * mu + 1e-6f);
    const float* gp = g0 + j * 32;
    u32* dst = (u32*)&L[HS_OFF + tok * 264 + j * 32];
#pragma unroll
    for (int d2 = 0; d2 < 16; ++d2) {
      float a = (v[2 * d2] - mu) * rs * gp[2 * d2];
      float b = (v[2 * d2 + 1] - mu) * rs * gp[2 * d2 + 1];
      dst[d2] = (u32)f2bf(a) | ((u32)f2bf(b) << 16);
    }
  }
  // (first GEMM1_CHUNK barrier covers hs visibility)

  // ---- Phase 1: q,k,v chunks (c = 0..11) with head-LN epilogue ----
  for (int c = 0; c < 12; ++c) {
    f32x4 a0 = {0.f, 0.f, 0.f, 0.f}, a1 = {0.f, 0.f, 0.f, 0.f};
    GEMM1_CHUNK(c, a0, a1);
    const int gc = c * 64 + ncl;
    const float bias0 = b_fused[gc + lr], bias1 = b_fused[gc + 16 + lr];
    const int arr = (c < 4) ? Q_OFF : ((c < 8) ? K_OFF : V_OFF);
    const int col = (c & 3) * 64 + ncl;
    if (c < 8) {
      const float* sc = (c < 4) ? lnq : lnk;
      const float s0 = sc[lr], s1 = sc[16 + lr];
#pragma unroll
      for (int r = 0; r < 4; ++r) {
        float v0 = a0[r] + bias0, v1 = a1[r] + bias1;
        float sum = v0 + v1, sq = v0 * v0 + v1 * v1;
#pragma unroll
        for (int m = 1; m < 16; m <<= 1) {
          sum += __shfl_xor(sum, m, 64);
          sq += __shfl_xor(sq, m, 64);
        }
        float mu = sum * (1.0f / 32.0f);
        float rs = rsqrtf(sq * (1.0f / 32.0f) - mu * mu + 1e-6f);
        int tokl = mrow + lg * 4 + r;
        L[arr + tokl * 264 + col + lr] = f2bf((v0 - mu) * rs * s0);
        L[arr + tokl * 264 + col + 16 + lr] = f2bf((v1 - mu) * rs * s1);
      }
    } else {
#pragma unroll
      for (int r = 0; r < 4; ++r) {
        int tokl = mrow + lg * 4 + r;
        L[arr + tokl * 264 + col + lr] = f2bf(a0[r] + bias0);
        L[arr + tokl * 264 + col + 16 + lr] = f2bf(a1[r] + bias1);
      }
    }
  }
  __syncthreads();  // q,k,v complete

  // ---- Phase 2: per-token 8x8 head attention; attn2 overwrites q slot ----
  {
    int tok = tid >> 3, ih = tid & 7;
    const u32* qp = (const u32*)&L[Q_OFF + tok * 264 + ih * 32];
    float qv[32];
#pragma unroll
    for (int d2 = 0; d2 < 16; ++d2) {
      u32 u = qp[d2];
      qv[2 * d2] = bf2f(u & 0xffffu);
      qv[2 * d2 + 1] = bf2f(u >> 16);
    }
    float S[8], mx = -1e30f;
#pragma unroll
    for (int j = 0; j < 8; ++j) {
      const u32* kp = (const u32*)&L[K_OFF + tok * 264 + j * 32];
      float acc = 0.f;
#pragma unroll
      for (int d2 = 0; d2 < 16; ++d2) {
        u32 u = kp[d2];
        acc += qv[2 * d2] * bf2f(u & 0xffffu) + qv[2 * d2 + 1] * bf2f(u >> 16);
      }
      S[j] = acc * 0.17677669529663687f;  // 1/sqrt(32)
      mx = fmaxf(mx, S[j]);
    }
    float p[8], sum = 0.f;
#pragma unroll
    for (int j = 0; j < 8; ++j) {
      p[j] = __expf(S[j] - mx);
      sum += p[j];
    }
    const float inv = 2.0f / sum;  // attn_h + attn_w = 2*attn
    float o[32];
#pragma unroll
    for (int d = 0; d < 32; ++d) o[d] = 0.f;
#pragma unroll
    for (int j = 0; j < 8; ++j) {
      const u32* vp = (const u32*)&L[V_OFF + tok * 264 + j * 32];
      float pj = p[j];
#pragma unroll
      for (int d2 = 0; d2 < 16; ++d2) {
        u32 u = vp[d2];
        o[2 * d2] += pj * bf2f(u & 0xffffu);
        o[2 * d2 + 1] += pj * bf2f(u >> 16);
      }
    }
    u32* op = (u32*)&L[Q_OFF + tok * 264 + ih * 32];  // own q slot: safe
#pragma unroll
    for (int d2 = 0; d2 < 16; ++d2)
      op[d2] = (u32)f2bf(o[2 * d2] * inv) | ((u32)f2bf(o[2 * d2 + 1] * inv) << 16);
  }
  __syncthreads();  // attn2 visible; k_s/v_s regions now dead -> overlays

  // ---- Phase 3: GEMM2 K=1280 (attn2 | gelu(ff) on the fly) ----
  const int nbase = (wv & 1) * 8;
  f32x4 acc[8];
#pragma unroll
  for (int i = 0; i < 8; ++i) acc[i] = (f32x4){0.f, 0.f, 0.f, 0.f};

  for (int c2 = 0; c2 < 20; ++c2) {
    if (c2 >= 4) {  // compute gelu(ff) chunk into gff overlay
      const int c = 8 + c2;  // GEMM1 chunk 12..27
      f32x4 f0 = {0.f, 0.f, 0.f, 0.f}, f1 = {0.f, 0.f, 0.f, 0.f};
      GEMM1_CHUNK(c, f0, f1);
      const float bias0 = b_fused[c * 64 + ncl + lr];
      const float bias1 = b_fused[c * 64 + ncl + 16 + lr];
#pragma unroll
      for (int r = 0; r < 4; ++r) {
        int tokl = mrow + lg * 4 + r;
        L[GFF_OFF + tokl * 72 + ncl + lr] = f2bf(gelu_f(f0[r] + bias0));
        L[GFF_OFF + tokl * 72 + ncl + 16 + lr] = f2bf(gelu_f(f1[r] + bias1));
      }
    }
    __syncthreads();  // gff visible; ws2 free of prior readers
    {                 // stage GEMM2 B chunk: wcT[0..255][c2*64 .. +63]
#pragma unroll
      for (int it = 0; it < 4; ++it) {
        int i = tid + it * 512;
        int r = i >> 3, q = i & 7;
        *(uint4*)&L[WS2_OFF + r * 72 + q * 8] =
            *(const uint4*)(wcT + (size_t)r * 1280 + c2 * 64 + q * 8);
      }
    }
    __syncthreads();
#pragma unroll
    for (int ks = 0; ks < 2; ++ks) {
      bf16x8 a;
      if (c2 < 4)
        a = *(const bf16x8*)&L[Q_OFF + (mrow + lr) * 264 + c2 * 64 + ks * 32 +
                               lg * 8];
      else
        a = *(const bf16x8*)&L[GFF_OFF + (mrow + lr) * 72 + ks * 32 + lg * 8];
#pragma unroll
      for (int nt = 0; nt < 8; ++nt) {
        bf16x8 b = *(const bf16x8*)&L[WS2_OFF + ((nbase + nt) * 16 + lr) * 72 +
                                      ks * 32 + lg * 8];
        acc[nt] = __builtin_amdgcn_mfma_f32_16x16x32_bf16(a, b, acc[nt], 0, 0, 0);
      }
    }
  }

  // ---- Epilogue: bias + gamma + residual ----
#pragma unroll
  for (int nt = 0; nt < 8; ++nt) {
    int col = (nbase + nt) * 16 + lr;
    float bb = b_out[col] + b_mlp[col];
    float gm = gamma[col];
#pragma unroll
    for (int r = 0; r < 4; ++r) {
      size_t tok = t0 + mrow + lg * 4 + r;
      out[tok * 256 + col] = x[tok * 256 + col] + gm * (acc[nt][r] + bb);
    }
  }
}

extern "C" void kernel_launch(void* const* d_in, const int* in_sizes, int n_in,
                              void* d_out, int out_size, void* d_ws,
                              size_t ws_size, hipStream_t stream) {
  const float* x = (const float*)d_in[0];
  const float* ln0_scale = (const float*)d_in[1];
  const float* w_fused = (const float*)d_in[2];
  const float* b_fused = (const float*)d_in[3];
  const float* lnq = (const float*)d_in[4];
  const float* lnk = (const float*)d_in[5];
  const float* w_out = (const float*)d_in[6];
  const float* b_out = (const float*)d_in[7];
  const float* w_mlp = (const float*)d_in[8];
  const float* b_mlp = (const float*)d_in[9];
  const float* gamma = (const float*)d_in[10];
  float* out = (float*)d_out;

  u16* wfT = (u16*)d_ws;                    // 1792*256 u16
  u16* wcT = wfT + (size_t)1792 * 256;      // 256*1280 u16; total ~1.5 MB

  kw_prep<<<3072, 256, 0, stream>>>(w_fused, w_out, w_mlp, wfT, wcT);
  k_mega<<<T_TOK / 64, 512, 0, stream>>>(x, ln0_scale, wfT, wcT, b_fused, lnq,
                                         lnk, b_out, b_mlp, gamma, out);
}

// Round 3
// 654.012 us; speedup vs baseline: 1.3029x; 1.3029x over previous
//
#include <hip/hip_runtime.h>

// AxialAttentionBlock mega-fused kernel, round 3.
// Insight (round 0): reference einsum makes "attention" a PER-TOKEN 8x8
// head-mix; attn_h == attn_w => 2*attn. Everything token-local => one fused
// kernel per 64-token tile.
// Round-3 changes: uniform 16KB double-buffered stage units via
// global_load_lds (pre-swizzled weight layout baked in kw_prep), h A-frags
// in registers (no hs tile), 1 barrier per unit with stage/compute overlap.

#define T_TOK 131072  // B*H*W

typedef __attribute__((ext_vector_type(8))) short bf16x8;
typedef __attribute__((ext_vector_type(4))) float f32x4;
typedef unsigned int u32;
typedef unsigned short u16;

__device__ __forceinline__ float bf2f(u32 u) {
  u32 v = u << 16;
  return __builtin_bit_cast(float, v);
}
__device__ __forceinline__ u16 f2bf(float f) {
  u32 u = __builtin_bit_cast(u32, f);
  return (u16)((u + 0x7fffu + ((u >> 16) & 1u)) >> 16);  // RNE
}
__device__ __forceinline__ float gelu_f(float x) {
  float t = 0.7978845608028654f * (x + 0.044715f * x * x * x);
  t = fminf(fmaxf(t, -15.f), 15.f);
  float e = __expf(2.0f * t);
  return 0.5f * x * (1.0f + (e - 1.0f) / (e + 1.0f));
}
__device__ __forceinline__ void gload16(const u16* g, u16* l) {
  __builtin_amdgcn_global_load_lds(
      (const __attribute__((address_space(1))) void*)g,
      (__attribute__((address_space(3))) void*)l, 16, 0, 0);
}

// ---------------- weight prep: staged + swizzled layout -------------------
// wfS: 56 blocks (c=0..27, h=0..1) of [64 rows r][128 kk], row-swizzled:
//   pos = block*8192 + r*128 + (kk ^ ((r&7)<<3));
//   value = w_fused[(h*128+kk)*1792 + c*64 + r]
// wcS: 40 blocks (c2=0..19, h=0..1) of [128 rl][64 kk]:
//   pos = block*8192 + rl*64 + (kk ^ ((rl&7)<<3)); n = h*128+rl; kg = c2*64+kk
//   value = kg<256 ? w_out[kg*256+n] : w_mlp[(kg-256)*256+n]
__global__ __launch_bounds__(256) void kw_prep(
    const float* __restrict__ w_fused, const float* __restrict__ w_out,
    const float* __restrict__ w_mlp, u16* __restrict__ wfS,
    u16* __restrict__ wcS) {
  int j = blockIdx.x * 256 + threadIdx.x;
  const int NF = 56 * 8192;
  if (j < NF) {
    int us = j >> 13, r = (j >> 7) & 63, kcs = j & 127;
    int kk = kcs ^ ((r & 7) << 3);
    int c = us >> 1, h = us & 1;
    wfS[j] = f2bf(w_fused[(h * 128 + kk) * 1792 + c * 64 + r]);
  } else {
    j -= NF;
    if (j < 40 * 8192) {
      int vs = j >> 13, rl = (j >> 6) & 127, kcs = j & 63;
      int kk = kcs ^ ((rl & 7) << 3);
      int c2 = vs >> 1, h = vs & 1;
      int n = h * 128 + rl, kg = c2 * 64 + kk;
      wcS[j] = f2bf(kg < 256 ? w_out[kg * 256 + n] : w_mlp[(kg - 256) * 256 + n]);
    }
  }
}

// ---------------- LDS layout (u16 units), total 134,144 B -----------------
#define Q_OFF 0       // q tile [64][264]; LN0 scratch first; attn2 in place
#define K_OFF 16896   // k tile [64][264]; gff overlay in phase 3
#define V_OFF 33792   // v tile [64][264]
#define SB 50688      // 2 stage bufs x 8192 u16 (16 KB each)
#define LDS_U16 67072
#define GFF_OFF K_OFF  // gelu(ff) chunk [64][72]

// stage-unit u -> global source block (8192 u16)
__device__ __forceinline__ const u16* unit_src(const u16* wfS, const u16* wcS,
                                               int u) {
  if (u < 24) return wfS + (size_t)u * 8192;       // GEMM1 chunks 0..11
  int t = u - 24;
  if (t < 8) return wcS + (size_t)t * 8192;        // ws2 c2=0..3
  t -= 8;
  int c2 = 4 + (t >> 2), r = t & 3;
  if (r < 2) return wfS + (size_t)((12 + (c2 - 4)) * 2 + r) * 8192;  // gelu G1
  return wcS + (size_t)(c2 * 2 + (r - 2)) * 8192;                    // ws2
}

#define ISSUE(U)                                                      \
  do {                                                                \
    const u16* _s = unit_src(wfS, wcS, (U));                          \
    u16* _d = &L[SB + (((U)&1) << 13) + ((tid >> 6) << 9)];           \
    gload16(_s + tid * 8, _d);                                        \
    gload16(_s + 4096 + tid * 8, _d + 4096);                          \
  } while (0)

#define G1_COMPUTE(Bbuf, H, A0, A1)                                          \
  _Pragma("unroll") for (int ks = 0; ks < 4; ++ks) {                         \
    bf16x8 a = hA[(H)*4 + ks];                                               \
    const int col = (ks * 32 + lg * 8) ^ xsw;                                \
    bf16x8 b0 = *(const bf16x8*)&(Bbuf)[(ncl + lr) * 128 + col];             \
    bf16x8 b1 = *(const bf16x8*)&(Bbuf)[(ncl + 16 + lr) * 128 + col];        \
    A0 = __builtin_amdgcn_mfma_f32_16x16x32_bf16(a, b0, A0, 0, 0, 0);        \
    A1 = __builtin_amdgcn_mfma_f32_16x16x32_bf16(a, b1, A1, 0, 0, 0);        \
  }

#define G2_COMPUTE(C2, Bbuf)                                                 \
  _Pragma("unroll") for (int ks = 0; ks < 2; ++ks) {                         \
    bf16x8 a;                                                                \
    if ((C2) < 4)                                                            \
      a = *(const bf16x8*)&L[Q_OFF + (mrow + lr) * 264 + (C2)*64 + ks * 32 + \
                             lg * 8];                                        \
    else                                                                     \
      a = *(const bf16x8*)&L[GFF_OFF + (mrow + lr) * 72 + ks * 32 + lg * 8]; \
    _Pragma("unroll") for (int nt = 0; nt < 8; ++nt) {                       \
      bf16x8 b =                                                             \
          *(const bf16x8*)&(Bbuf)[(nt * 16 + lr) * 64 +                      \
                                  ((ks * 32 + lg * 8) ^ xsw)];               \
      acc[nt] =                                                              \
          __builtin_amdgcn_mfma_f32_16x16x32_bf16(a, b, acc[nt], 0, 0, 0);   \
    }                                                                        \
  }

__global__ __launch_bounds__(512) void k_mega(
    const float* __restrict__ x, const float* __restrict__ g0,
    const u16* __restrict__ wfS, const u16* __restrict__ wcS,
    const float* __restrict__ b_fused, const float* __restrict__ lnq,
    const float* __restrict__ lnk, const float* __restrict__ b_out,
    const float* __restrict__ b_mlp, const float* __restrict__ gamma,
    float* __restrict__ out) {
  __shared__ u16 L[LDS_U16];
  const int tid = threadIdx.x;
  const size_t t0 = (size_t)blockIdx.x * 64;
  const int wv = tid >> 6, l = tid & 63, lr = l & 15, lg = l >> 4;
  const int mrow = (wv >> 1) * 16;
  const int hh = wv & 1;
  const int ncl = hh * 32;
  const int xsw = (lr & 7) << 3;

  // prefetch stage unit 0 while LN0 runs
  ISSUE(0);

  // ---- Phase 0: LN0 -> Q-region scratch ----
  {
    int tok = tid >> 3, j = tid & 7;
    const float* xp = x + (t0 + tok) * 256 + j * 32;
    float v[32];
#pragma unroll
    for (int i = 0; i < 8; ++i) {
      float4 f = ((const float4*)xp)[i];
      v[4 * i] = f.x; v[4 * i + 1] = f.y; v[4 * i + 2] = f.z; v[4 * i + 3] = f.w;
    }
    float s = 0.f, ss = 0.f;
#pragma unroll
    for (int i = 0; i < 32; ++i) { s += v[i]; ss += v[i] * v[i]; }
#pragma unroll
    for (int m = 1; m < 8; m <<= 1) {
      s += __shfl_xor(s, m, 64);
      ss += __shfl_xor(ss, m, 64);
    }
    float mu = s * (1.0f / 256.0f);
    float rs = rsqrtf(ss * (1.0f / 256.0f) - mu * mu + 1e-6f);
    const float* gp = g0 + j * 32;
    u32* dst = (u32*)&L[Q_OFF + tok * 264 + j * 32];
#pragma unroll
    for (int d2 = 0; d2 < 16; ++d2) {
      float a = (v[2 * d2] - mu) * rs * gp[2 * d2];
      float b = (v[2 * d2 + 1] - mu) * rs * gp[2 * d2 + 1];
      dst[d2] = (u32)f2bf(a) | ((u32)f2bf(b) << 16);
    }
  }
  __syncthreads();

  // ---- h A-fragments -> registers (live for the whole kernel) ----
  bf16x8 hA[8];
#pragma unroll
  for (int ks = 0; ks < 8; ++ks)
    hA[ks] = *(const bf16x8*)&L[Q_OFF + (mrow + lr) * 264 + ks * 32 + lg * 8];

  int u = 0;

  // ---- Phase 1: q,k,v chunks c=0..11 (units 0..23) ----
  for (int c = 0; c < 12; ++c) {
    f32x4 a0 = {0.f, 0.f, 0.f, 0.f}, a1 = {0.f, 0.f, 0.f, 0.f};
#pragma unroll
    for (int h = 0; h < 2; ++h) {
      __syncthreads();
      ISSUE(u + 1);
      const u16* B = &L[SB + ((u & 1) << 13)];
      G1_COMPUTE(B, h, a0, a1);
      ++u;
    }
    // chunk epilogue (inside unit 2c+1's compute window)
    const int gc = c * 64 + ncl;
    const float bias0 = b_fused[gc + lr], bias1 = b_fused[gc + 16 + lr];
    const int arr = (c < 4) ? Q_OFF : ((c < 8) ? K_OFF : V_OFF);
    const int col = (c & 3) * 64 + ncl;
    if (c < 8) {  // q/k: per-head LN over 32 cols
      const float* sc = (c < 4) ? lnq : lnk;
      const float s0 = sc[lr], s1 = sc[16 + lr];
#pragma unroll
      for (int r = 0; r < 4; ++r) {
        float v0 = a0[r] + bias0, v1 = a1[r] + bias1;
        float sum = v0 + v1, sq = v0 * v0 + v1 * v1;
#pragma unroll
        for (int m = 1; m < 16; m <<= 1) {
          sum += __shfl_xor(sum, m, 64);
          sq += __shfl_xor(sq, m, 64);
        }
        float mu = sum * (1.0f / 32.0f);
        float rs = rsqrtf(sq * (1.0f / 32.0f) - mu * mu + 1e-6f);
        int tokl = mrow + lg * 4 + r;
        L[arr + tokl * 264 + col + lr] = f2bf((v0 - mu) * rs * s0);
        L[arr + tokl * 264 + col + 16 + lr] = f2bf((v1 - mu) * rs * s1);
      }
    } else {  // v
#pragma unroll
      for (int r = 0; r < 4; ++r) {
        int tokl = mrow + lg * 4 + r;
        L[arr + tokl * 264 + col + lr] = f2bf(a0[r] + bias0);
        L[arr + tokl * 264 + col + 16 + lr] = f2bf(a1[r] + bias1);
      }
    }
  }

  f32x4 acc[8];
#pragma unroll
  for (int i = 0; i < 8; ++i) acc[i] = (f32x4){0.f, 0.f, 0.f, 0.f};

  // ---- Phase 2 + c2=0 (units 24,25): attention interleaved ----
  __syncthreads();  // q,k,v published; unit 24 resident
  ISSUE(25);
  {
    int tok = tid >> 3, ih = tid & 7;
    const u32* qp = (const u32*)&L[Q_OFF + tok * 264 + ih * 32];
    float qv[32];
#pragma unroll
    for (int d2 = 0; d2 < 16; ++d2) {
      u32 w = qp[d2];
      qv[2 * d2] = bf2f(w & 0xffffu);
      qv[2 * d2 + 1] = bf2f(w >> 16);
    }
    float S[8], mx = -1e30f;
#pragma unroll
    for (int j = 0; j < 8; ++j) {
      const u32* kp = (const u32*)&L[K_OFF + tok * 264 + j * 32];
      float a = 0.f;
#pragma unroll
      for (int d2 = 0; d2 < 16; ++d2) {
        u32 w = kp[d2];
        a += qv[2 * d2] * bf2f(w & 0xffffu) + qv[2 * d2 + 1] * bf2f(w >> 16);
      }
      S[j] = a * 0.17677669529663687f;
      mx = fmaxf(mx, S[j]);
    }
    float p[8], sum = 0.f;
#pragma unroll
    for (int j = 0; j < 8; ++j) {
      p[j] = __expf(S[j] - mx);
      sum += p[j];
    }
    const float inv = 2.0f / sum;  // attn_h + attn_w = 2*attn
    float o[32];
#pragma unroll
    for (int d = 0; d < 32; ++d) o[d] = 0.f;
#pragma unroll
    for (int j = 0; j < 8; ++j) {
      const u32* vp = (const u32*)&L[V_OFF + tok * 264 + j * 32];
      float pj = p[j];
#pragma unroll
      for (int d2 = 0; d2 < 16; ++d2) {
        u32 w = vp[d2];
        o[2 * d2] += pj * bf2f(w & 0xffffu);
        o[2 * d2 + 1] += pj * bf2f(w >> 16);
      }
    }
    u32* op = (u32*)&L[Q_OFF + tok * 264 + ih * 32];  // own q slot
#pragma unroll
    for (int d2 = 0; d2 < 16; ++d2)
      op[d2] = (u32)f2bf(o[2 * d2] * inv) | ((u32)f2bf(o[2 * d2 + 1] * inv) << 16);
  }
  __syncthreads();  // attn2 visible
  if (hh == 0) { const u16* B = &L[SB]; G2_COMPUTE(0, B); }          // unit 24
  __syncthreads();
  ISSUE(26);
  if (hh == 1) { const u16* B = &L[SB + 8192]; G2_COMPUTE(0, B); }   // unit 25
  u = 26;

  // ---- Phase 3: c2 = 1..19 ----
  for (int c2 = 1; c2 < 20; ++c2) {
    if (c2 >= 4) {  // gelu(ff) chunk via GEMM1 on hA regs
      f32x4 f0 = {0.f, 0.f, 0.f, 0.f}, f1 = {0.f, 0.f, 0.f, 0.f};
#pragma unroll
      for (int h = 0; h < 2; ++h) {
        __syncthreads();
        ISSUE(u + 1);
        const u16* B = &L[SB + ((u & 1) << 13)];
        G1_COMPUTE(B, h, f0, f1);
        ++u;
      }
      const int cc = 8 + c2;  // GEMM1 chunk 12..27
      const float bias0 = b_fused[cc * 64 + ncl + lr];
      const float bias1 = b_fused[cc * 64 + ncl + 16 + lr];
#pragma unroll
      for (int r = 0; r < 4; ++r) {
        int tokl = mrow + lg * 4 + r;
        L[GFF_OFF + tokl * 72 + ncl + lr] = f2bf(gelu_f(f0[r] + bias0));
        L[GFF_OFF + tokl * 72 + ncl + 16 + lr] = f2bf(gelu_f(f1[r] + bias1));
      }
    }
#pragma unroll
    for (int h = 0; h < 2; ++h) {
      __syncthreads();
      if (u + 1 < 96) ISSUE(u + 1);
      if (hh == h) {
        const u16* B = &L[SB + ((u & 1) << 13)];
        G2_COMPUTE(c2, B);
      }
      ++u;
    }
  }

  // ---- Epilogue: bias + gamma + residual ----
#pragma unroll
  for (int nt = 0; nt < 8; ++nt) {
    int col = (hh * 8 + nt) * 16 + lr;
    float bb = b_out[col] + b_mlp[col];
    float gm = gamma[col];
#pragma unroll
    for (int r = 0; r < 4; ++r) {
      size_t tok = t0 + mrow + lg * 4 + r;
      out[tok * 256 + col] = x[tok * 256 + col] + gm * (acc[nt][r] + bb);
    }
  }
}

extern "C" void kernel_launch(void* const* d_in, const int* in_sizes, int n_in,
                              void* d_out, int out_size, void* d_ws,
                              size_t ws_size, hipStream_t stream) {
  const float* x = (const float*)d_in[0];
  const float* ln0_scale = (const float*)d_in[1];
  const float* w_fused = (const float*)d_in[2];
  const float* b_fused = (const float*)d_in[3];
  const float* lnq = (const float*)d_in[4];
  const float* lnk = (const float*)d_in[5];
  const float* w_out = (const float*)d_in[6];
  const float* b_out = (const float*)d_in[7];
  const float* w_mlp = (const float*)d_in[8];
  const float* b_mlp = (const float*)d_in[9];
  const float* gamma = (const float*)d_in[10];
  float* out = (float*)d_out;

  u16* wfS = (u16*)d_ws;                      // 56*8192 u16
  u16* wcS = wfS + (size_t)56 * 8192;         // 40*8192 u16; total ~1.5 MB

  kw_prep<<<3072, 256, 0, stream>>>(w_fused, w_out, w_mlp, wfS, wcS);
  k_mega<<<T_TOK / 64, 512, 0, stream>>>(x, ln0_scale, wfS, wcS, b_fused, lnq,
                                         lnk, b_out, b_mlp, gamma, out);
}

// Round 4
// 546.878 us; speedup vs baseline: 1.5581x; 1.1959x over previous
//
#include <hip/hip_runtime.h>

// AxialAttentionBlock mega-fused kernel, round 4.
// Insight (round 0): reference einsum makes "attention" a PER-TOKEN 8x8
// head-mix; attn_h == attn_w => 2*attn. Everything token-local => one fused
// kernel per 64-token tile.
// Round-4: counted-vmcnt pipeline (T4): 3 stage buffers, issue depth 2,
// s_waitcnt vmcnt(2)+s_barrier instead of __syncthreads (no vmcnt(0) drain).
// Constants staged in LDS (no vmem in loop). Q/K/V/gff XOR-swizzled stride
// 256/64 (bank-conflict-free A-reads). Balanced G2 (all waves every unit).

#define T_TOK 131072  // B*H*W

typedef __attribute__((ext_vector_type(8))) short bf16x8;
typedef __attribute__((ext_vector_type(4))) float f32x4;
typedef unsigned int u32;
typedef unsigned short u16;

__device__ __forceinline__ float bf2f(u32 u) {
  u32 v = u << 16;
  return __builtin_bit_cast(float, v);
}
__device__ __forceinline__ u16 f2bf(float f) {
  u32 u = __builtin_bit_cast(u32, f);
  return (u16)((u + 0x7fffu + ((u >> 16) & 1u)) >> 16);  // RNE
}
__device__ __forceinline__ float gelu_f(float x) {
  float t = 0.7978845608028654f * (x + 0.044715f * x * x * x);
  t = fminf(fmaxf(t, -15.f), 15.f);
  float e = __expf(2.0f * t);
  return 0.5f * x * (1.0f + (e - 1.0f) / (e + 1.0f));
}
__device__ __forceinline__ void gload16(const u16* g, u16* l) {
  __builtin_amdgcn_global_load_lds(
      (const __attribute__((address_space(1))) void*)g,
      (__attribute__((address_space(3))) void*)l, 16, 0, 0);
}

// ---------------- weight prep: staged + swizzled layout (unchanged) -------
__global__ __launch_bounds__(256) void kw_prep(
    const float* __restrict__ w_fused, const float* __restrict__ w_out,
    const float* __restrict__ w_mlp, u16* __restrict__ wfS,
    u16* __restrict__ wcS) {
  int j = blockIdx.x * 256 + threadIdx.x;
  const int NF = 56 * 8192;
  if (j < NF) {
    int us = j >> 13, r = (j >> 7) & 63, kcs = j & 127;
    int kk = kcs ^ ((r & 7) << 3);
    int c = us >> 1, h = us & 1;
    wfS[j] = f2bf(w_fused[(h * 128 + kk) * 1792 + c * 64 + r]);
  } else {
    j -= NF;
    if (j < 40 * 8192) {
      int vs = j >> 13, rl = (j >> 6) & 127, kcs = j & 63;
      int kk = kcs ^ ((rl & 7) << 3);
      int c2 = vs >> 1, h = vs & 1;
      int n = h * 128 + rl, kg = c2 * 64 + kk;
      wcS[j] = f2bf(kg < 256 ? w_out[kg * 256 + n] : w_mlp[(kg - 256) * 256 + n]);
    }
  }
}

// ---------------- LDS layout (u16 units), 157,952 B -----------------------
#define Q_OFF 0       // q tile [64][256] swizzled; LN0 scratch; attn2 in place
#define K_OFF 16384   // k tile; gff overlay in phase 3
#define V_OFF 32768   // v tile
#define SB 49152      // 3 stage bufs x 8192 u16 (16 KB each)
#define CONST_U16 73728  // 2624 f32: b_fused|lnq|lnk|b_out|b_mlp|gamma
#define LDS_U16 78976
#define GFF_OFF K_OFF  // gelu(ff) chunk [64][64] swizzled

// stage-unit u -> global source block (8192 u16)
__device__ __forceinline__ const u16* unit_src(const u16* wfS, const u16* wcS,
                                               int u) {
  if (u < 24) return wfS + (size_t)u * 8192;  // G1 chunks 0..11
  int t = u - 24;
  if (t < 8) return wcS + (size_t)t * 8192;   // W2 c2=0..3
  t -= 8;
  int c2 = 4 + (t >> 2), r = t & 3;
  if (r < 2) return wfS + (size_t)((8 + c2) * 2 + r) * 8192;  // gelu G1
  return wcS + (size_t)(c2 * 2 + (r - 2)) * 8192;             // W2
}

#define ISSUE(U)                                              \
  do {                                                        \
    const u16* _s = unit_src(wfS, wcS, (U));                  \
    u16* _d = &L[SB + ((U) % 3) * 8192 + ((tid >> 6) << 9)];  \
    gload16(_s + tid * 8, _d);                                \
    gload16(_s + 4096 + tid * 8, _d + 4096);                  \
  } while (0)

#define WAITBAR2                                                   \
  do {                                                             \
    asm volatile("s_waitcnt vmcnt(2) lgkmcnt(0)" ::: "memory");    \
    __builtin_amdgcn_s_barrier();                                  \
    __builtin_amdgcn_sched_barrier(0);                             \
  } while (0)
#define WAITBAR0                                                   \
  do {                                                             \
    asm volatile("s_waitcnt vmcnt(0) lgkmcnt(0)" ::: "memory");    \
    __builtin_amdgcn_s_barrier();                                  \
    __builtin_amdgcn_sched_barrier(0);                             \
  } while (0)

#define G1_COMPUTE(BUF, H, A0, A1)                                           \
  _Pragma("unroll") for (int ks = 0; ks < 4; ++ks) {                         \
    bf16x8 a = hA[(H)*4 + ks];                                               \
    const int col = (ks * 32 + lg * 8) ^ xsw;                                \
    bf16x8 b0 = *(const bf16x8*)&(BUF)[(ncl + lr) * 128 + col];              \
    bf16x8 b1 = *(const bf16x8*)&(BUF)[(ncl + 16 + lr) * 128 + col];         \
    A0 = __builtin_amdgcn_mfma_f32_16x16x32_bf16(a, b0, A0, 0, 0, 0);        \
    A1 = __builtin_amdgcn_mfma_f32_16x16x32_bf16(a, b1, A1, 0, 0, 0);        \
  }

// balanced G2: every wave computes acc[(H)*4+nt], n-rows hh*64+nt*16+lr
#define G2_STEP(ABASE, ASTRIDE, ACOL0, H, BUF)                               \
  _Pragma("unroll") for (int ks = 0; ks < 2; ++ks) {                         \
    bf16x8 a = *(const bf16x8*)&L[(ABASE) + (mrow + lr) * (ASTRIDE) +        \
                                  (((ACOL0) + ks * 32 + lg * 8) ^ xsw)];     \
    _Pragma("unroll") for (int nt = 0; nt < 4; ++nt) {                       \
      bf16x8 b = *(const bf16x8*)&(BUF)[(hh * 64 + nt * 16 + lr) * 64 +      \
                                        ((ks * 32 + lg * 8) ^ xsw)];         \
      acc[(H)*4 + nt] =                                                      \
          __builtin_amdgcn_mfma_f32_16x16x32_bf16(a, b, acc[(H)*4 + nt], 0,  \
                                                  0, 0);                     \
    }                                                                        \
  }

__global__ __launch_bounds__(512) void k_mega(
    const float* __restrict__ x, const float* __restrict__ g0,
    const u16* __restrict__ wfS, const u16* __restrict__ wcS,
    const float* __restrict__ b_fused, const float* __restrict__ lnq,
    const float* __restrict__ lnk, const float* __restrict__ b_out,
    const float* __restrict__ b_mlp, const float* __restrict__ gamma,
    float* __restrict__ out) {
  __shared__ u16 L[LDS_U16];
  const int tid = threadIdx.x;
  const size_t t0 = (size_t)blockIdx.x * 64;
  const int wv = tid >> 6, l = tid & 63, lr = l & 15, lg = l >> 4;
  const int mrow = (wv >> 1) * 16;
  const int hh = wv & 1;
  const int ncl = hh * 32;
  const int xsw = (lr & 7) << 3;
  float* CF = (float*)&L[CONST_U16];

  // ---- Prologue: stage constants into LDS ----
  for (int i = tid; i < 2624; i += 512) {
    float v;
    if (i < 1792) v = b_fused[i];
    else if (i < 1824) v = lnq[i - 1792];
    else if (i < 1856) v = lnk[i - 1824];
    else if (i < 2112) v = b_out[i - 1856];
    else if (i < 2368) v = b_mlp[i - 2112];
    else v = gamma[i - 2368];
    CF[i] = v;
  }

  // ---- Phase 0: LN0 -> Q-region scratch (swizzled) ----
  {
    int tok = tid >> 3, j = tid & 7;
    int xq = (tok & 7) << 3;
    const float* xp = x + (t0 + tok) * 256 + j * 32;
    float v[32];
#pragma unroll
    for (int i = 0; i < 8; ++i) {
      float4 f = ((const float4*)xp)[i];
      v[4 * i] = f.x; v[4 * i + 1] = f.y; v[4 * i + 2] = f.z; v[4 * i + 3] = f.w;
    }
    float s = 0.f, ss = 0.f;
#pragma unroll
    for (int i = 0; i < 32; ++i) { s += v[i]; ss += v[i] * v[i]; }
#pragma unroll
    for (int m = 1; m < 8; m <<= 1) {
      s += __shfl_xor(s, m, 64);
      ss += __shfl_xor(ss, m, 64);
    }
    float mu = s * (1.0f / 256.0f);
    float rs = rsqrtf(ss * (1.0f / 256.0f) - mu * mu + 1e-6f);
    const float* gp = g0 + j * 32;
#pragma unroll
    for (int g = 0; g < 4; ++g) {
      uint4 w;
      u32* we = (u32*)&w;
#pragma unroll
      for (int e = 0; e < 4; ++e) {
        float a = (v[g * 8 + 2 * e] - mu) * rs * gp[g * 8 + 2 * e];
        float b = (v[g * 8 + 2 * e + 1] - mu) * rs * gp[g * 8 + 2 * e + 1];
        we[e] = (u32)f2bf(a) | ((u32)f2bf(b) << 16);
      }
      *(uint4*)&L[Q_OFF + tok * 256 + ((j * 32 + g * 8) ^ xq)] = w;
    }
  }
  __syncthreads();  // consts + hs visible

  // ---- h A-fragments -> registers ----
  bf16x8 hA[8];
#pragma unroll
  for (int ks = 0; ks < 8; ++ks)
    hA[ks] = *(const bf16x8*)&L[Q_OFF + (mrow + lr) * 256 +
                                ((ks * 32 + lg * 8) ^ xsw)];

  ISSUE(0);
  ISSUE(1);
  int u = 0;
  f32x4 acc[8];

  // ---- Phase 1: q,k,v chunks c=0..11 (units 0..23) ----
  for (int c = 0; c < 12; ++c) {
    f32x4 a0 = {0.f, 0.f, 0.f, 0.f}, a1 = {0.f, 0.f, 0.f, 0.f};
#pragma unroll
    for (int h = 0; h < 2; ++h) {
      WAITBAR2;
      ISSUE(u + 2);
      const u16* B = &L[SB + (u % 3) * 8192];
      G1_COMPUTE(B, h, a0, a1);
      ++u;
    }
    const int gc = c * 64 + ncl;
    const float bias0 = CF[gc + lr], bias1 = CF[gc + 16 + lr];
    const int arr = (c < 4) ? Q_OFF : ((c < 8) ? K_OFF : V_OFF);
    const int col = (c & 3) * 64 + ncl;
    if (c < 8) {  // q/k: per-head LN over 32 cols
      const int sco = (c < 4) ? 1792 : 1824;
      const float s0 = CF[sco + lr], s1 = CF[sco + 16 + lr];
#pragma unroll
      for (int r = 0; r < 4; ++r) {
        float v0 = a0[r] + bias0, v1 = a1[r] + bias1;
        float sum = v0 + v1, sq = v0 * v0 + v1 * v1;
#pragma unroll
        for (int m = 1; m < 16; m <<= 1) {
          sum += __shfl_xor(sum, m, 64);
          sq += __shfl_xor(sq, m, 64);
        }
        float mu = sum * (1.0f / 32.0f);
        float rs = rsqrtf(sq * (1.0f / 32.0f) - mu * mu + 1e-6f);
        int tokl = mrow + lg * 4 + r;
        int sw = (tokl & 7) << 3;
        L[arr + tokl * 256 + ((col + lr) ^ sw)] = f2bf((v0 - mu) * rs * s0);
        L[arr + tokl * 256 + ((col + 16 + lr) ^ sw)] = f2bf((v1 - mu) * rs * s1);
      }
    } else {  // v
#pragma unroll
      for (int r = 0; r < 4; ++r) {
        int tokl = mrow + lg * 4 + r;
        int sw = (tokl & 7) << 3;
        L[arr + tokl * 256 + ((col + lr) ^ sw)] = f2bf(a0[r] + bias0);
        L[arr + tokl * 256 + ((col + 16 + lr) ^ sw)] = f2bf(a1[r] + bias1);
      }
    }
  }

  // ---- Seam: unit 24 ready; attention; then G2 c2=0 ----
  WAITBAR2;   // drains unit 24 (25 in flight)
  ISSUE(26);
  {
    int tok = tid >> 3, ih = tid & 7;
    int xq = (tok & 7) << 3;
    const int rq = Q_OFF + tok * 256, rk = K_OFF + tok * 256,
              rv = V_OFF + tok * 256;
    float qv[32];
#pragma unroll
    for (int g = 0; g < 4; ++g) {
      uint4 w = *(const uint4*)&L[rq + ((ih * 32 + g * 8) ^ xq)];
      const u32* we = (const u32*)&w;
#pragma unroll
      for (int e = 0; e < 4; ++e) {
        qv[g * 8 + 2 * e] = bf2f(we[e] & 0xffffu);
        qv[g * 8 + 2 * e + 1] = bf2f(we[e] >> 16);
      }
    }
    float S[8], mx = -1e30f;
#pragma unroll
    for (int j = 0; j < 8; ++j) {
      float a = 0.f;
#pragma unroll
      for (int g = 0; g < 4; ++g) {
        uint4 w = *(const uint4*)&L[rk + ((j * 32 + g * 8) ^ xq)];
        const u32* we = (const u32*)&w;
#pragma unroll
        for (int e = 0; e < 4; ++e)
          a += qv[g * 8 + 2 * e] * bf2f(we[e] & 0xffffu) +
               qv[g * 8 + 2 * e + 1] * bf2f(we[e] >> 16);
      }
      S[j] = a * 0.17677669529663687f;  // 1/sqrt(32)
      mx = fmaxf(mx, S[j]);
    }
    float p[8], sum = 0.f;
#pragma unroll
    for (int j = 0; j < 8; ++j) {
      p[j] = __expf(S[j] - mx);
      sum += p[j];
    }
    const float inv = 2.0f / sum;  // attn_h + attn_w = 2*attn
    float o[32];
#pragma unroll
    for (int d = 0; d < 32; ++d) o[d] = 0.f;
#pragma unroll
    for (int j = 0; j < 8; ++j) {
      float pj = p[j];
#pragma unroll
      for (int g = 0; g < 4; ++g) {
        uint4 w = *(const uint4*)&L[rv + ((j * 32 + g * 8) ^ xq)];
        const u32* we = (const u32*)&w;
#pragma unroll
        for (int e = 0; e < 4; ++e) {
          o[g * 8 + 2 * e] += pj * bf2f(we[e] & 0xffffu);
          o[g * 8 + 2 * e + 1] += pj * bf2f(we[e] >> 16);
        }
      }
    }
#pragma unroll
    for (int g = 0; g < 4; ++g) {
      uint4 w;
      u32* we = (u32*)&w;
#pragma unroll
      for (int e = 0; e < 4; ++e)
        we[e] = (u32)f2bf(o[g * 8 + 2 * e] * inv) |
                ((u32)f2bf(o[g * 8 + 2 * e + 1] * inv) << 16);
      *(uint4*)&L[rq + ((ih * 32 + g * 8) ^ xq)] = w;  // own q slot
    }
  }
  asm volatile("s_waitcnt lgkmcnt(0)" ::: "memory");
  __builtin_amdgcn_s_barrier();
  __builtin_amdgcn_sched_barrier(0);

#pragma unroll
  for (int i = 0; i < 8; ++i) acc[i] = (f32x4){0.f, 0.f, 0.f, 0.f};
  { const u16* B = &L[SB + 0 * 8192]; G2_STEP(Q_OFF, 256, 0, 0, B); }  // u24
  WAITBAR2;  // drains 25
  ISSUE(27);
  { const u16* B = &L[SB + 1 * 8192]; G2_STEP(Q_OFF, 256, 0, 1, B); }  // u25
  u = 26;

  // ---- c2 = 1..3: A from attn2 (Q tile) ----
  for (int c2 = 1; c2 < 4; ++c2) {
#pragma unroll
    for (int h = 0; h < 2; ++h) {
      WAITBAR2;
      ISSUE(u + 2);
      const u16* B = &L[SB + (u % 3) * 8192];
      G2_STEP(Q_OFF, 256, c2 * 64, h, B);
      ++u;
    }
  }

  // ---- c2 = 4..19: gelu(ff) on the fly, then W2 ----
  for (int c2 = 4; c2 < 20; ++c2) {
    f32x4 f0 = {0.f, 0.f, 0.f, 0.f}, f1 = {0.f, 0.f, 0.f, 0.f};
#pragma unroll
    for (int r = 0; r < 2; ++r) {
      WAITBAR2;
      if (u + 2 < 96) ISSUE(u + 2);
      const u16* B = &L[SB + (u % 3) * 8192];
      G1_COMPUTE(B, r, f0, f1);
      ++u;
    }
    const int cc = 8 + c2;
    const float bias0 = CF[cc * 64 + ncl + lr];
    const float bias1 = CF[cc * 64 + ncl + 16 + lr];
#pragma unroll
    for (int r = 0; r < 4; ++r) {
      int tokl = mrow + lg * 4 + r;
      int sw = (tokl & 7) << 3;
      L[GFF_OFF + tokl * 64 + ((ncl + lr) ^ sw)] = f2bf(gelu_f(f0[r] + bias0));
      L[GFF_OFF + tokl * 64 + ((ncl + 16 + lr) ^ sw)] =
          f2bf(gelu_f(f1[r] + bias1));
    }
#pragma unroll
    for (int h = 0; h < 2; ++h) {
      if (u == 95) { WAITBAR0; }
      else { WAITBAR2; if (u + 2 < 96) ISSUE(u + 2); }
      const u16* B = &L[SB + (u % 3) * 8192];
      G2_STEP(GFF_OFF, 64, 0, h, B);
      ++u;
    }
  }

  // ---- Epilogue: bias + gamma + residual ----
#pragma unroll
  for (int j = 0; j < 8; ++j) {
    int h = j >> 2, nt = j & 3;
    int col = h * 128 + hh * 64 + nt * 16 + lr;
    float bb = CF[1856 + col] + CF[2112 + col];
    float gm = CF[2368 + col];
#pragma unroll
    for (int r = 0; r < 4; ++r) {
      size_t tok = t0 + mrow + lg * 4 + r;
      out[tok * 256 + col] = x[tok * 256 + col] + gm * (acc[j][r] + bb);
    }
  }
}

extern "C" void kernel_launch(void* const* d_in, const int* in_sizes, int n_in,
                              void* d_out, int out_size, void* d_ws,
                              size_t ws_size, hipStream_t stream) {
  const float* x = (const float*)d_in[0];
  const float* ln0_scale = (const float*)d_in[1];
  const float* w_fused = (const float*)d_in[2];
  const float* b_fused = (const float*)d_in[3];
  const float* lnq = (const float*)d_in[4];
  const float* lnk = (const float*)d_in[5];
  const float* w_out = (const float*)d_in[6];
  const float* b_out = (const float*)d_in[7];
  const float* w_mlp = (const float*)d_in[8];
  const float* b_mlp = (const float*)d_in[9];
  const float* gamma = (const float*)d_in[10];
  float* out = (float*)d_out;

  u16* wfS = (u16*)d_ws;                   // 56*8192 u16
  u16* wcS = wfS + (size_t)56 * 8192;      // 40*8192 u16; total ~1.5 MB

  kw_prep<<<3072, 256, 0, stream>>>(w_fused, w_out, w_mlp, wfS, wcS);
  k_mega<<<T_TOK / 64, 512, 0, stream>>>(x, ln0_scale, wfS, wcS, b_fused, lnq,
                                         lnk, b_out, b_mlp, gamma, out);
}